// Round 14
// baseline (302.419 us; speedup 1.0000x reference)
//
#include <hip/hip_runtime.h>
#include <hip/hip_fp16.h>

#define NN 40000
#define NE 640000
#define HID 128
#define EB ((NE + 255) / 256)         // 2500
#define ECAP 1536                     // staged edge-index capacity per block

typedef __attribute__((ext_vector_type(8)))  short short8;
typedef __attribute__((ext_vector_type(4)))  short short4v;
typedef __attribute__((ext_vector_type(16))) float floatx16;
typedef unsigned int uint;

__device__ __forceinline__ short f2bf(float f) {
    union { float f; unsigned u; } c; c.f = f;
    unsigned u = c.u;
    unsigned r = (u + 0x7FFF + ((u >> 16) & 1)) >> 16;   // RNE
    return (short)r;
}
__device__ __forceinline__ float bf2f(short h) {
    union { unsigned u; float f; } c;
    c.u = ((unsigned)(unsigned short)h) << 16;
    return c.f;
}
__device__ __forceinline__ float2 h2f2(uint u) {
    union { uint u; __half2 h; } c; c.u = u;
    return __half22float2(c.h);
}
__device__ __forceinline__ void splits(float f, short* hi, short* lo) {
    short h = f2bf(f);
    *hi = h;
    *lo = f2bf(f - bf2f(h));
}
__device__ __forceinline__ void unpack8(uint4 a, uint4 b, short8* h, short8* l) {
    short8 H, L;
    H[0] = (short)(a.x >> 16); L[0] = (short)a.x;
    H[1] = (short)(a.y >> 16); L[1] = (short)a.y;
    H[2] = (short)(a.z >> 16); L[2] = (short)a.z;
    H[3] = (short)(a.w >> 16); L[3] = (short)a.w;
    H[4] = (short)(b.x >> 16); L[4] = (short)b.x;
    H[5] = (short)(b.y >> 16); L[5] = (short)b.y;
    H[6] = (short)(b.z >> 16); L[6] = (short)b.z;
    H[7] = (short)(b.w >> 16); L[7] = (short)b.w;
    *h = H; *l = L;
}

// W fragment swizzle (HW-verified r9-r15)
__device__ __forceinline__ int wswz(int o, int k) {
    int chunk = k >> 4, half = (k >> 3) & 1, j = k & 7;
    int ct = o >> 5, m31 = o & 31;
    int lane = half * 32 + m31;
    return (((chunk * 4 + ct) * 64 + lane) * 8 + j);
}

// accumulate one uint4 (8 fp16 channels) into two float4 accumulators
#define ACC4(u, A, B)                                                     \
    { float2 f0 = h2f2(u.x), f1 = h2f2(u.y);                              \
      float2 f2 = h2f2(u.z), f3 = h2f2(u.w);                              \
      A.x += f0.x; A.y += f0.y; A.z += f1.x; A.w += f1.y;                 \
      B.x += f2.x; B.y += f2.y; B.z += f3.x; B.w += f3.y; }

// edge loop body (r4 shape — best measured)
#define GBODY(IDX)                                                        \
        for (; e + 8 <= hi; e += 8) {                                     \
            int s0 = IDX(e + sub);     int s1 = IDX(e + 2 + sub);         \
            int s2 = IDX(e + 4 + sub); int s3 = IDX(e + 6 + sub);         \
            uint4 u0 = hp[(size_t)s0 * 16 + c16];                         \
            uint4 u1 = hp[(size_t)s1 * 16 + c16];                         \
            uint4 u2 = hp[(size_t)s2 * 16 + c16];                         \
            uint4 u3 = hp[(size_t)s3 * 16 + c16];                         \
            ACC4(u0, a0, a1); ACC4(u1, b0, b1);                           \
            ACC4(u2, c0, c1); ACC4(u3, d0, d1);                           \
        }                                                                 \
        for (; e + 2 <= hi; e += 2) {                                     \
            int s0 = IDX(e + sub);                                        \
            uint4 u0 = hp[(size_t)s0 * 16 + c16];                         \
            ACC4(u0, a0, a1);                                             \
        }                                                                 \
        if (sub == 0 && e < hi) {                                         \
            int s0 = IDX(e);                                              \
            uint4 u0 = hp[(size_t)s0 * 16 + c16];                         \
            ACC4(u0, b0, b1);                                             \
        }

#define IDXS(j) sE[(j)]
#define IDXG(j) esrc[lo0 + (j)]

// edge-gather phase: agg rows -> split-bf16 fragments in sAh/sAl[0..4095]
#define GATHER_PHASE                                                          \
    if (t == 0) sCtr = 0;                                                     \
    if (t < 33) sRP[t] = row_ptr[r0 + t];                                     \
    __syncthreads();                                                          \
    const int lo0 = sRP[0];                                                   \
    const int nE  = sRP[32] - lo0;                                            \
    const int nStage = nE < ECAP ? nE : ECAP;                                 \
    for (int i = t; i < nStage; i += 256) sE[i] = esrc[lo0 + i];              \
    __syncthreads();                                                          \
    const bool fast = (nE <= ECAP);                                           \
    for (;;) {                                                                \
        int n = 0;                                                            \
        if ((t & 31) == 0) n = atomicAdd(&sCtr, 1);                           \
        n = __shfl(n, 0, 32);                                                 \
        if (n >= 32) break;                                                   \
        const int lo = sRP[n] - lo0, hi = sRP[n + 1] - lo0;                   \
        float4 a0 = make_float4(0,0,0,0), a1 = make_float4(0,0,0,0);          \
        float4 b0 = make_float4(0,0,0,0), b1 = make_float4(0,0,0,0);          \
        float4 c0 = make_float4(0,0,0,0), c1 = make_float4(0,0,0,0);          \
        float4 d0 = make_float4(0,0,0,0), d1 = make_float4(0,0,0,0);          \
        int e = lo;                                                           \
        if (fast) { GBODY(IDXS) } else { GBODY(IDXG) }                        \
        float4 v0, v1;                                                        \
        v0.x = (a0.x + b0.x) + (c0.x + d0.x);                                 \
        v0.y = (a0.y + b0.y) + (c0.y + d0.y);                                 \
        v0.z = (a0.z + b0.z) + (c0.z + d0.z);                                 \
        v0.w = (a0.w + b0.w) + (c0.w + d0.w);                                 \
        v1.x = (a1.x + b1.x) + (c1.x + d1.x);                                 \
        v1.y = (a1.y + b1.y) + (c1.y + d1.y);                                 \
        v1.z = (a1.z + b1.z) + (c1.z + d1.z);                                 \
        v1.w = (a1.w + b1.w) + (c1.w + d1.w);                                 \
        v0.x += __shfl_down(v0.x, 16, 32);                                    \
        v0.y += __shfl_down(v0.y, 16, 32);                                    \
        v0.z += __shfl_down(v0.z, 16, 32);                                    \
        v0.w += __shfl_down(v0.w, 16, 32);                                    \
        v1.x += __shfl_down(v1.x, 16, 32);                                    \
        v1.y += __shfl_down(v1.y, 16, 32);                                    \
        v1.z += __shfl_down(v1.z, 16, 32);                                    \
        v1.w += __shfl_down(v1.w, 16, 32);                                    \
        if (sub == 0) {                                                       \
            short8 H, L;                                                      \
            short hh, ll;                                                     \
            splits(v0.x, &hh, &ll); H[0] = hh; L[0] = ll;                     \
            splits(v0.y, &hh, &ll); H[1] = hh; L[1] = ll;                     \
            splits(v0.z, &hh, &ll); H[2] = hh; L[2] = ll;                     \
            splits(v0.w, &hh, &ll); H[3] = hh; L[3] = ll;                     \
            splits(v1.x, &hh, &ll); H[4] = hh; L[4] = ll;                     \
            splits(v1.y, &hh, &ll); H[5] = hh; L[5] = ll;                     \
            splits(v1.z, &hh, &ll); H[6] = hh; L[6] = ll;                     \
            splits(v1.w, &hh, &ll); H[7] = hh; L[7] = ll;                     \
            const int off = c16 * 256 + n * 8;                                \
            *(short8*)(sAh + off) = H;                                        \
            *(short8*)(sAl + off) = L;                                        \
        }                                                                     \
    }                                                                         \
    __syncthreads();

#define MFMA_LOOP(NC, WQ, ACC)                                                \
    _Pragma("unroll")                                                         \
    for (int c = 0; c < NC; ++c) {                                            \
        short8 ah = *(const short8*)(sAh + (c * 2 + half) * 256 + m31 * 8);   \
        short8 al = *(const short8*)(sAl + (c * 2 + half) * 256 + m31 * 8);   \
        const uint* wr = WQ + ((size_t)(c * 4 + wv) * 64 + lane) * 8;         \
        uint4 w0 = *(const uint4*)(wr);                                       \
        uint4 w1 = *(const uint4*)(wr + 4);                                   \
        short8 bh, bl;                                                        \
        unpack8(w0, w1, &bh, &bl);                                            \
        ACC = __builtin_amdgcn_mfma_f32_32x32x16_bf16(ah, bh, ACC, 0, 0, 0);  \
        ACC = __builtin_amdgcn_mfma_f32_32x32x16_bf16(al, bh, ACC, 0, 0, 0);  \
        ACC = __builtin_amdgcn_mfma_f32_32x32x16_bf16(ah, bl, ACC, 0, 0, 0);  \
    }

// ---------------- gather #1: fused gather + W2 linear -> fp16 global --------
__global__ __launch_bounds__(256, 4) void fused_gather_lin_kernel(
    const __half* __restrict__ h, const int* __restrict__ row_ptr,
    const int* __restrict__ esrc, const uint* __restrict__ Wq,
    const float* __restrict__ bias, __half* __restrict__ out)
{
    __shared__ short sAh[4096];
    __shared__ short sAl[4096];
    __shared__ int   sE[ECAP];
    __shared__ int   sRP[33];
    __shared__ int   sCtr;
    const int t   = threadIdx.x;
    const int r0  = blockIdx.x * 32;
    const int c16 = t & 15;
    const int sub = (t >> 4) & 1;
    const uint4* hp = (const uint4*)h;   // row = 16 uint4

    GATHER_PHASE

    const int wv   = t >> 6;
    const int lane = t & 63;
    const int m31  = lane & 31;
    const int half = lane >> 5;
    floatx16 acc;
    #pragma unroll
    for (int i = 0; i < 16; ++i) acc[i] = 0.f;
    MFMA_LOOP(8, Wq, acc)
    const int col = wv * 32 + m31;
    const float bb = bias[col];
    #pragma unroll
    for (int reg = 0; reg < 16; ++reg) {
        int row = (reg & 3) + 8 * (reg >> 2) + 4 * half;
        float v = fmaxf(acc[reg] + bb, 0.f);
        out[(size_t)(r0 + row) * HID + col] = __float2half(v);
    }
}

// ---------------- gather #2 fused with folded linear / cat+head -------------
// v6: l2 never touches global. MFMA#1 acc -> relu+bias -> split-bf16 LDS
// (channels 128..255); l1 staged from h(=bB) into channels 0..127; MFMA#2
// with folded W. HEAD=false: h1 -> outA (conv0). HEAD=true: gbuf + head
// -> outF (conv1). Saves 2 dispatches + 2x(bC write + bC re-read).
template<bool HEAD>
__global__ __launch_bounds__(256, HEAD ? 3 : 4) void gather2_fused_kernel(
    const __half* __restrict__ h, const int* __restrict__ row_ptr,
    const int* __restrict__ esrc, const uint* __restrict__ Wq,
    const float* __restrict__ bias, const uint* __restrict__ Wq2,
    const float* __restrict__ bias2, __half* __restrict__ outA,
    const float* __restrict__ f2, const float* __restrict__ f2b,
    float* __restrict__ outF)
{
    __shared__ short sAh[8192];
    __shared__ short sAl[8192];
    __shared__ __align__(16) char upool[HEAD ? (32 * 129 * 4) : (ECAP * 4)];
    __shared__ int   sRP[33];
    __shared__ int   sCtr;
    int*   sE   = (int*)upool;            // edge loop only
    float* gbuf = (float*)upool;          // HEAD tail only (sE dead by then)
    const int t   = threadIdx.x;
    const int r0  = blockIdx.x * 32;
    const int c16 = t & 15;
    const int sub = (t >> 4) & 1;
    const uint4* hp = (const uint4*)h;    // row = 16 uint4

    GATHER_PHASE                          // ends with S1

    const int wv   = t >> 6;
    const int lane = t & 63;
    const int m31  = lane & 31;
    const int half = lane >> 5;
    const int col  = wv * 32 + m31;

    // MFMA#1: l2 = relu(W2 . agg + b2); write fragments to second half.
    {
        floatx16 acc1;
        #pragma unroll
        for (int i = 0; i < 16; ++i) acc1[i] = 0.f;
        MFMA_LOOP(8, Wq, acc1)
        const float bb = bias[col];
        #pragma unroll
        for (int reg = 0; reg < 16; ++reg) {
            int row = (reg & 3) + 8 * (reg >> 2) + 4 * half;
            float v = fmaxf(acc1[reg] + bb, 0.f);
            short hh, ll;
            splits(v, &hh, &ll);
            int off2 = (16 + (col >> 3)) * 256 + row * 8 + (col & 7);
            sAh[off2] = hh;
            sAl[off2] = ll;
        }
    }
    __syncthreads();   // S2: MFMA#1 reads + l2 writes complete

    // stage l1 (= h rows r0..r0+31) into first half (channels 0..127)
    #pragma unroll
    for (int i = 0; i < 4; ++i) {
        int v = t + 256 * i;              // 0..1023
        int row = v >> 5, q = v & 31;     // kk = q*4
        uint2 u = *(const uint2*)((const __half*)h + (size_t)(r0 + row) * 128 + q * 4);
        float2 f0 = h2f2(u.x), f1 = h2f2(u.y);
        int off = (q >> 1) * 256 + row * 8 + (q & 1) * 4;
        short4v hi, lo;
        short hh, ll;
        splits(f0.x, &hh, &ll); hi.x = hh; lo.x = ll;
        splits(f0.y, &hh, &ll); hi.y = hh; lo.y = ll;
        splits(f1.x, &hh, &ll); hi.z = hh; lo.z = ll;
        splits(f1.y, &hh, &ll); hi.w = hh; lo.w = ll;
        *(short4v*)(sAh + off) = hi;
        *(short4v*)(sAl + off) = lo;
    }
    __syncthreads();   // S3: cat(l1,l2) fragments ready

    floatx16 acc2;
    #pragma unroll
    for (int i = 0; i < 16; ++i) acc2[i] = 0.f;
    MFMA_LOOP(16, Wq2, acc2)

    const float b2 = bias2[col];
    if (!HEAD) {
        #pragma unroll
        for (int reg = 0; reg < 16; ++reg) {
            int row = (reg & 3) + 8 * (reg >> 2) + 4 * half;
            float v = fmaxf(acc2[reg] + b2, 0.f);
            outA[(size_t)(r0 + row) * HID + col] = __float2half(v);
        }
    } else {
        #pragma unroll
        for (int reg = 0; reg < 16; ++reg) {
            int row = (reg & 3) + 8 * (reg >> 2) + 4 * half;
            gbuf[row * 129 + col] = fmaxf(acc2[reg] + b2, 0.f);
        }
        __syncthreads();
        const int node = t >> 3;
        const int seg  = t & 7;
        const float* gr = gbuf + node * 129 + seg * 16;
        float a = 0.f;
        #pragma unroll
        for (int i = 0; i < 16; ++i) a += gr[i] * f2[seg * 16 + i];
        a += __shfl_down(a, 4, 8);
        a += __shfl_down(a, 2, 8);
        a += __shfl_down(a, 1, 8);
        if (seg == 0) outF[r0 + node] = a + f2b[0];
    }
}

// ---------------- merged prep: wprep + wfoldA + wfoldB + rank-hist ----------
__global__ __launch_bounds__(256) void prep_kernel(
    const float* __restrict__ c0w2, const float* __restrict__ c1w2,
    const float* __restrict__ c1w1, const float* __restrict__ c0w3,
    const float* __restrict__ c0b3, const float* __restrict__ c1b1,
    const float* __restrict__ fw1,  const float* __restrict__ c1w3,
    const float* __restrict__ c1b3, const float* __restrict__ fb1,
    const int* __restrict__ dst, int* __restrict__ cnt, int* __restrict__ rank,
    uint* __restrict__ wp, uint* __restrict__ p_Wa, uint* __restrict__ p_Wb,
    float* __restrict__ f_ba, float* __restrict__ f_bb)
{
    const int b = blockIdx.x;
    const int t = threadIdx.x;
    if (b < 128) {
        int i = b * 256 + t;
        const float* src = (i < 16384) ? c0w2 : c1w2;
        int off = (i < 16384) ? 0 : 16384;
        int L = i - off;
        int o = L >> 7, k = L & 127;
        short hh, ll;
        splits(src[L], &hh, &ll);
        wp[off + wswz(o, k)] = ((uint)(unsigned short)hh << 16) | (uint)(unsigned short)ll;
    } else if (b < 384) {
        const bool isA = (b < 256);
        const int o = b - (isA ? 128 : 256);
        const float* A   = isA ? c1w1 : fw1;
        const float* B   = isA ? c0w3 : c1w3;
        const float* bi  = isA ? c0b3 : c1b3;
        const float* bo  = isA ? c1b1 : fb1;
        uint*  W  = isA ? p_Wa : p_Wb;
        float* bb = isA ? f_ba : f_bb;
        const float* Ar = A + o * 128;
        float s = 0.f;
        for (int j = 0; j < 128; ++j) s += Ar[j] * B[j * 256 + t];
        short hh, ll;
        splits(s, &hh, &ll);
        W[wswz(o, t)] = ((uint)(unsigned short)hh << 16) | (uint)(unsigned short)ll;
        if (t == 0) {
            float sb = 0.f;
            for (int j = 0; j < 128; ++j) sb += Ar[j] * bi[j];
            bb[o] = sb + bo[o];
        }
    } else {
        int e = (b - 384) * 256 + t;
        if (e < NE) rank[e] = atomicAdd(&cnt[dst[e]], 1);
    }
}

// ---------------- single-block full exclusive scan ---------------------------
#define SCHUNK 40   // 1024 threads x 40 >= NN
__global__ __launch_bounds__(1024) void scan_kernel(
    const int* __restrict__ cnt, int* __restrict__ row_ptr)
{
    __shared__ int s[1024];
    const int t = threadIdx.x;
    const int base = t * SCHUNK;
    int sum = 0;
    if (base < NN) {
        int n = min(SCHUNK, NN - base);
        #pragma unroll 8
        for (int j = 0; j < n; ++j) sum += cnt[base + j];
    }
    s[t] = sum;
    __syncthreads();
    #pragma unroll
    for (int off = 1; off < 1024; off <<= 1) {
        int x = (t >= off) ? s[t - off] : 0;
        __syncthreads();
        s[t] += x;
        __syncthreads();
    }
    int run = (t == 0) ? 0 : s[t - 1];
    if (base < NN) {
        int n = min(SCHUNK, NN - base);
        for (int j = 0; j < n; ++j) {
            int v = cnt[base + j];
            row_ptr[base + j] = run;
            run += v;
        }
    }
    if (t == 1023) row_ptr[NN] = s[1023];
}

// ---------------- merged fill (rank-based, no atomics) + embed --------------
__global__ __launch_bounds__(256) void fill_embed_kernel(
    const int* __restrict__ src, const int* __restrict__ dst,
    const int* __restrict__ row_ptr, const int* __restrict__ rank,
    int* __restrict__ esrc,
    const float* __restrict__ x, const float* __restrict__ w1,
    const float* __restrict__ b1, __half* __restrict__ h0)
{
    const int b = blockIdx.x;
    const int t = threadIdx.x;
    if (b < EB) {
        int e = b * 256 + t;
        if (e < NE) {
            int d = dst[e];
            esrc[row_ptr[d] + rank[e]] = src[e];
        }
    } else {
        __shared__ float xs[2][88];
        const int hf = t >> 7;
        const int m  = t & 127;
        const int r0 = (b - EB) * 16 + hf * 8;
        for (int i = m; i < 88; i += 128) {
            int r = i / 11, k = i - r * 11;
            xs[hf][i] = x[(size_t)(r0 + r) * 11 + k];
        }
        __syncthreads();
        float acc[8] = {};
        const float* Wm = w1 + m * 11;
        #pragma unroll
        for (int k = 0; k < 11; ++k) {
            float w = Wm[k];
            #pragma unroll
            for (int r = 0; r < 8; ++r) acc[r] += xs[hf][r * 11 + k] * w;
        }
        const float bias = b1[m];
        #pragma unroll
        for (int r = 0; r < 8; ++r) {
            float v = fmaxf(acc[r] + bias, 0.f);
            h0[(size_t)(r0 + r) * HID + m] = __float2half(v);
        }
    }
}

extern "C" void kernel_launch(void* const* d_in, const int* in_sizes, int n_in,
                              void* d_out, int out_size, void* d_ws, size_t ws_size,
                              hipStream_t stream)
{
    const float* x     = (const float*)d_in[0];
    const int*   eidx  = (const int*)d_in[1];
    const float* c0_w1 = (const float*)d_in[2],  *c0_b1 = (const float*)d_in[3];
    const float* c0_w2 = (const float*)d_in[4],  *c0_b2 = (const float*)d_in[5];
    const float* c0_w3 = (const float*)d_in[6],  *c0_b3 = (const float*)d_in[7];
    const float* c1_w1 = (const float*)d_in[8],  *c1_b1 = (const float*)d_in[9];
    const float* c1_w2 = (const float*)d_in[10], *c1_b2 = (const float*)d_in[11];
    const float* c1_w3 = (const float*)d_in[12], *c1_b3 = (const float*)d_in[13];
    const float* f_w1  = (const float*)d_in[14], *f_b1  = (const float*)d_in[15];
    const float* f_w2  = (const float*)d_in[16], *f_b2  = (const float*)d_in[17];
    const int* src = eidx;
    const int* dst = eidx + NE;
    float* out = (float*)d_out;

    const size_t BUF = (size_t)NN * HID;
    __half* bA = (__half*)d_ws;
    __half* bB = bA + BUF;
    __half* bC = bB + BUF;                   // rank scratch only (fused pipeline)
    int* row_ptr  = (int*)(bC + BUF);        // NN+1
    int* cnt      = row_ptr + (NN + 1);      // NN (hist)
    int* esrc     = cnt + NN;                // NE
    uint* wp      = (uint*)(esrc + NE);

    uint* p_c0w2 = wp + 0;          // 16384
    uint* p_c1w2 = wp + 16384;      // 16384
    uint* p_Wa   = wp + 32768;      // 32768 (c1_w1 · c0_w3)
    uint* p_Wb   = wp + 65536;      // 32768 (f_w1 · c1_w3)
    float* f_ba  = (float*)(wp + 98304);  // 128
    float* f_bb  = f_ba + 128;            // 128

    int* rank = (int*)bC;

    const int nbl = (NN + 31) / 32;   // 1250

    // ---- prep (weights + rank-hist) + scan + fill/embed ----
    (void)hipMemsetAsync(cnt, 0, NN * sizeof(int), stream);
    prep_kernel<<<384 + EB, 256, 0, stream>>>(
        c0_w2, c1_w2, c1_w1, c0_w3, c0_b3, c1_b1,
        f_w1, c1_w3, c1_b3, f_b1, dst, cnt, rank, wp, p_Wa, p_Wb, f_ba, f_bb);
    scan_kernel<<<1, 1024, 0, stream>>>(cnt, row_ptr);
    fill_embed_kernel<<<EB + 2500, 256, 0, stream>>>(
        src, dst, row_ptr, rank, esrc, x, c0_w1, c0_b1, bA);      // h0 = bA

    // ---- conv0: gather l1_0; fused gather l2_0 + folded lin -> h1 (bA) ----
    fused_gather_lin_kernel<<<nbl, 256, 0, stream>>>(bA, row_ptr, esrc, p_c0w2, c0_b2, bB);
    gather2_fused_kernel<false><<<nbl, 256, 0, stream>>>(
        bB, row_ptr, esrc, p_c0w2, c0_b2, p_Wa, f_ba, bA, nullptr, nullptr, nullptr);

    // ---- conv1: gather l1_1; fused gather l2_1 + cat GEMM + head -> out ----
    fused_gather_lin_kernel<<<nbl, 256, 0, stream>>>(bA, row_ptr, esrc, p_c1w2, c1_b2, bB);
    gather2_fused_kernel<true><<<nbl, 256, 0, stream>>>(
        bB, row_ptr, esrc, p_c1w2, c1_b2, p_Wb, f_bb, nullptr, f_w2, f_b2, out);
}

// Round 15
// 299.454 us; speedup vs baseline: 1.0099x; 1.0099x over previous
//
#include <hip/hip_runtime.h>
#include <hip/hip_fp16.h>

#define NN 40000
#define NE 640000
#define HID 128
#define EB ((NE + 255) / 256)         // 2500
#define ECAP 1408                     // staged edge-index capacity per block
#define FS 260                        // fragment group stride (shorts); 256+4
                                      // pad breaks the 512B bank alignment
                                      // (r14: 3.68M LDS conflicts on l2 write)

typedef __attribute__((ext_vector_type(8)))  short short8;
typedef __attribute__((ext_vector_type(4)))  short short4v;
typedef __attribute__((ext_vector_type(16))) float floatx16;
typedef unsigned int uint;

__device__ __forceinline__ short f2bf(float f) {
    union { float f; unsigned u; } c; c.f = f;
    unsigned u = c.u;
    unsigned r = (u + 0x7FFF + ((u >> 16) & 1)) >> 16;   // RNE
    return (short)r;
}
__device__ __forceinline__ float bf2f(short h) {
    union { unsigned u; float f; } c;
    c.u = ((unsigned)(unsigned short)h) << 16;
    return c.f;
}
__device__ __forceinline__ float2 h2f2(uint u) {
    union { uint u; __half2 h; } c; c.u = u;
    return __half22float2(c.h);
}
__device__ __forceinline__ void splits(float f, short* hi, short* lo) {
    short h = f2bf(f);
    *hi = h;
    *lo = f2bf(f - bf2f(h));
}
__device__ __forceinline__ void unpack8(uint4 a, uint4 b, short8* h, short8* l) {
    short8 H, L;
    H[0] = (short)(a.x >> 16); L[0] = (short)a.x;
    H[1] = (short)(a.y >> 16); L[1] = (short)a.y;
    H[2] = (short)(a.z >> 16); L[2] = (short)a.z;
    H[3] = (short)(a.w >> 16); L[3] = (short)a.w;
    H[4] = (short)(b.x >> 16); L[4] = (short)b.x;
    H[5] = (short)(b.y >> 16); L[5] = (short)b.y;
    H[6] = (short)(b.z >> 16); L[6] = (short)b.z;
    H[7] = (short)(b.w >> 16); L[7] = (short)b.w;
    *h = H; *l = L;
}

// W fragment swizzle (HW-verified r9-r15)
__device__ __forceinline__ int wswz(int o, int k) {
    int chunk = k >> 4, half = (k >> 3) & 1, j = k & 7;
    int ct = o >> 5, m31 = o & 31;
    int lane = half * 32 + m31;
    return (((chunk * 4 + ct) * 64 + lane) * 8 + j);
}

// accumulate one uint4 (8 fp16 channels) into two float4 accumulators
#define ACC4(u, A, B)                                                     \
    { float2 f0 = h2f2(u.x), f1 = h2f2(u.y);                              \
      float2 f2 = h2f2(u.z), f3 = h2f2(u.w);                              \
      A.x += f0.x; A.y += f0.y; A.z += f1.x; A.w += f1.y;                 \
      B.x += f2.x; B.y += f2.y; B.z += f3.x; B.w += f3.y; }

// edge loop body (r4 shape — best measured)
#define GBODY(IDX)                                                        \
        for (; e + 8 <= hi; e += 8) {                                     \
            int s0 = IDX(e + sub);     int s1 = IDX(e + 2 + sub);         \
            int s2 = IDX(e + 4 + sub); int s3 = IDX(e + 6 + sub);         \
            uint4 u0 = hp[(size_t)s0 * 16 + c16];                         \
            uint4 u1 = hp[(size_t)s1 * 16 + c16];                         \
            uint4 u2 = hp[(size_t)s2 * 16 + c16];                         \
            uint4 u3 = hp[(size_t)s3 * 16 + c16];                         \
            ACC4(u0, a0, a1); ACC4(u1, b0, b1);                           \
            ACC4(u2, c0, c1); ACC4(u3, d0, d1);                           \
        }                                                                 \
        for (; e + 2 <= hi; e += 2) {                                     \
            int s0 = IDX(e + sub);                                        \
            uint4 u0 = hp[(size_t)s0 * 16 + c16];                         \
            ACC4(u0, a0, a1);                                             \
        }                                                                 \
        if (sub == 0 && e < hi) {                                         \
            int s0 = IDX(e);                                              \
            uint4 u0 = hp[(size_t)s0 * 16 + c16];                         \
            ACC4(u0, b0, b1);                                             \
        }

#define IDXS(j) sE[(j)]
#define IDXG(j) esrc[lo0 + (j)]

// edge-gather phase: agg rows -> split-bf16 fragments in groups 0..15
#define GATHER_PHASE                                                          \
    if (t == 0) sCtr = 0;                                                     \
    if (t < 33) sRP[t] = row_ptr[r0 + t];                                     \
    __syncthreads();                                                          \
    const int lo0 = sRP[0];                                                   \
    const int nE  = sRP[32] - lo0;                                            \
    const int nStage = nE < ECAP ? nE : ECAP;                                 \
    for (int i = t; i < nStage; i += 256) sE[i] = esrc[lo0 + i];              \
    __syncthreads();                                                          \
    const bool fast = (nE <= ECAP);                                           \
    for (;;) {                                                                \
        int n = 0;                                                            \
        if ((t & 31) == 0) n = atomicAdd(&sCtr, 1);                           \
        n = __shfl(n, 0, 32);                                                 \
        if (n >= 32) break;                                                   \
        const int lo = sRP[n] - lo0, hi = sRP[n + 1] - lo0;                   \
        float4 a0 = make_float4(0,0,0,0), a1 = make_float4(0,0,0,0);          \
        float4 b0 = make_float4(0,0,0,0), b1 = make_float4(0,0,0,0);          \
        float4 c0 = make_float4(0,0,0,0), c1 = make_float4(0,0,0,0);          \
        float4 d0 = make_float4(0,0,0,0), d1 = make_float4(0,0,0,0);          \
        int e = lo;                                                           \
        if (fast) { GBODY(IDXS) } else { GBODY(IDXG) }                        \
        float4 v0, v1;                                                        \
        v0.x = (a0.x + b0.x) + (c0.x + d0.x);                                 \
        v0.y = (a0.y + b0.y) + (c0.y + d0.y);                                 \
        v0.z = (a0.z + b0.z) + (c0.z + d0.z);                                 \
        v0.w = (a0.w + b0.w) + (c0.w + d0.w);                                 \
        v1.x = (a1.x + b1.x) + (c1.x + d1.x);                                 \
        v1.y = (a1.y + b1.y) + (c1.y + d1.y);                                 \
        v1.z = (a1.z + b1.z) + (c1.z + d1.z);                                 \
        v1.w = (a1.w + b1.w) + (c1.w + d1.w);                                 \
        v0.x += __shfl_down(v0.x, 16, 32);                                    \
        v0.y += __shfl_down(v0.y, 16, 32);                                    \
        v0.z += __shfl_down(v0.z, 16, 32);                                    \
        v0.w += __shfl_down(v0.w, 16, 32);                                    \
        v1.x += __shfl_down(v1.x, 16, 32);                                    \
        v1.y += __shfl_down(v1.y, 16, 32);                                    \
        v1.z += __shfl_down(v1.z, 16, 32);                                    \
        v1.w += __shfl_down(v1.w, 16, 32);                                    \
        if (sub == 0) {                                                       \
            short8 H, L;                                                      \
            short hh, ll;                                                     \
            splits(v0.x, &hh, &ll); H[0] = hh; L[0] = ll;                     \
            splits(v0.y, &hh, &ll); H[1] = hh; L[1] = ll;                     \
            splits(v0.z, &hh, &ll); H[2] = hh; L[2] = ll;                     \
            splits(v0.w, &hh, &ll); H[3] = hh; L[3] = ll;                     \
            splits(v1.x, &hh, &ll); H[4] = hh; L[4] = ll;                     \
            splits(v1.y, &hh, &ll); H[5] = hh; L[5] = ll;                     \
            splits(v1.z, &hh, &ll); H[6] = hh; L[6] = ll;                     \
            splits(v1.w, &hh, &ll); H[7] = hh; L[7] = ll;                     \
            const int off = c16 * FS + n * 8;                                 \
            *(short8*)(sAh + off) = H;                                        \
            *(short8*)(sAl + off) = L;                                        \
        }                                                                     \
    }                                                                         \
    __syncthreads();

#define MFMA_LOOP(NC, WQ, ACC)                                                \
    _Pragma("unroll")                                                         \
    for (int c = 0; c < NC; ++c) {                                            \
        short8 ah = *(const short8*)(sAh + (c * 2 + half) * FS + m31 * 8);    \
        short8 al = *(const short8*)(sAl + (c * 2 + half) * FS + m31 * 8);    \
        const uint* wr = WQ + ((size_t)(c * 4 + wv) * 64 + lane) * 8;         \
        uint4 w0 = *(const uint4*)(wr);                                       \
        uint4 w1 = *(const uint4*)(wr + 4);                                   \
        short8 bh, bl;                                                        \
        unpack8(w0, w1, &bh, &bl);                                            \
        ACC = __builtin_amdgcn_mfma_f32_32x32x16_bf16(ah, bh, ACC, 0, 0, 0);  \
        ACC = __builtin_amdgcn_mfma_f32_32x32x16_bf16(al, bh, ACC, 0, 0, 0);  \
        ACC = __builtin_amdgcn_mfma_f32_32x32x16_bf16(ah, bl, ACC, 0, 0, 0);  \
    }

// ---------------- gather #1: fused gather + W2 linear -> fp16 global --------
__global__ __launch_bounds__(256, 4) void fused_gather_lin_kernel(
    const __half* __restrict__ h, const int* __restrict__ row_ptr,
    const int* __restrict__ esrc, const uint* __restrict__ Wq,
    const float* __restrict__ bias, __half* __restrict__ out)
{
    __shared__ short sAh[16 * FS];
    __shared__ short sAl[16 * FS];
    __shared__ int   sE[ECAP];
    __shared__ int   sRP[33];
    __shared__ int   sCtr;
    const int t   = threadIdx.x;
    const int r0  = blockIdx.x * 32;
    const int c16 = t & 15;
    const int sub = (t >> 4) & 1;
    const uint4* hp = (const uint4*)h;   // row = 16 uint4

    GATHER_PHASE

    const int wv   = t >> 6;
    const int lane = t & 63;
    const int m31  = lane & 31;
    const int half = lane >> 5;
    floatx16 acc;
    #pragma unroll
    for (int i = 0; i < 16; ++i) acc[i] = 0.f;
    MFMA_LOOP(8, Wq, acc)
    const int col = wv * 32 + m31;
    const float bb = bias[col];
    #pragma unroll
    for (int reg = 0; reg < 16; ++reg) {
        int row = (reg & 3) + 8 * (reg >> 2) + 4 * half;
        float v = fmaxf(acc[reg] + bb, 0.f);
        out[(size_t)(r0 + row) * HID + col] = __float2half(v);
    }
}

// ---------------- gather #2 fused with folded linear / cat+head -------------
// v7: FS=260 breaks the 512B group-stride bank alignment on the l2 fragment
// write (r14: 3.68M SQ_LDS_BANK_CONFLICT, ~16-way on 4 banks -> ~4-way).
template<bool HEAD>
__global__ __launch_bounds__(256, HEAD ? 3 : 4) void gather2_fused_kernel(
    const __half* __restrict__ h, const int* __restrict__ row_ptr,
    const int* __restrict__ esrc, const uint* __restrict__ Wq,
    const float* __restrict__ bias, const uint* __restrict__ Wq2,
    const float* __restrict__ bias2, __half* __restrict__ outA,
    const float* __restrict__ f2, const float* __restrict__ f2b,
    float* __restrict__ outF)
{
    __shared__ short sAh[32 * FS];
    __shared__ short sAl[32 * FS];
    __shared__ __align__(16) char upool[HEAD ? (32 * 129 * 4) : (ECAP * 4)];
    __shared__ int   sRP[33];
    __shared__ int   sCtr;
    int*   sE   = (int*)upool;            // edge loop only
    float* gbuf = (float*)upool;          // HEAD tail only (sE dead by then)
    const int t   = threadIdx.x;
    const int r0  = blockIdx.x * 32;
    const int c16 = t & 15;
    const int sub = (t >> 4) & 1;
    const uint4* hp = (const uint4*)h;    // row = 16 uint4

    GATHER_PHASE                          // ends with S1

    const int wv   = t >> 6;
    const int lane = t & 63;
    const int m31  = lane & 31;
    const int half = lane >> 5;
    const int col  = wv * 32 + m31;

    // MFMA#1: l2 = relu(W2 . agg + b2); write fragments to groups 16..31.
    {
        floatx16 acc1;
        #pragma unroll
        for (int i = 0; i < 16; ++i) acc1[i] = 0.f;
        MFMA_LOOP(8, Wq, acc1)
        const float bb = bias[col];
        #pragma unroll
        for (int reg = 0; reg < 16; ++reg) {
            int row = (reg & 3) + 8 * (reg >> 2) + 4 * half;
            float v = fmaxf(acc1[reg] + bb, 0.f);
            short hh, ll;
            splits(v, &hh, &ll);
            int off2 = (16 + (col >> 3)) * FS + row * 8 + (col & 7);
            sAh[off2] = hh;
            sAl[off2] = ll;
        }
    }
    __syncthreads();   // S2: MFMA#1 reads + l2 writes complete

    // stage l1 (= h rows r0..r0+31) into groups 0..15
    #pragma unroll
    for (int i = 0; i < 4; ++i) {
        int v = t + 256 * i;              // 0..1023
        int row = v >> 5, q = v & 31;     // kk = q*4
        uint2 u = *(const uint2*)((const __half*)h + (size_t)(r0 + row) * 128 + q * 4);
        float2 f0 = h2f2(u.x), f1 = h2f2(u.y);
        int off = (q >> 1) * FS + row * 8 + (q & 1) * 4;
        short4v hi, lo;
        short hh, ll;
        splits(f0.x, &hh, &ll); hi.x = hh; lo.x = ll;
        splits(f0.y, &hh, &ll); hi.y = hh; lo.y = ll;
        splits(f1.x, &hh, &ll); hi.z = hh; lo.z = ll;
        splits(f1.y, &hh, &ll); hi.w = hh; lo.w = ll;
        *(short4v*)(sAh + off) = hi;
        *(short4v*)(sAl + off) = lo;
    }
    __syncthreads();   // S3: cat(l1,l2) fragments ready

    floatx16 acc2;
    #pragma unroll
    for (int i = 0; i < 16; ++i) acc2[i] = 0.f;
    MFMA_LOOP(16, Wq2, acc2)

    const float b2 = bias2[col];
    if (!HEAD) {
        #pragma unroll
        for (int reg = 0; reg < 16; ++reg) {
            int row = (reg & 3) + 8 * (reg >> 2) + 4 * half;
            float v = fmaxf(acc2[reg] + b2, 0.f);
            outA[(size_t)(r0 + row) * HID + col] = __float2half(v);
        }
    } else {
        #pragma unroll
        for (int reg = 0; reg < 16; ++reg) {
            int row = (reg & 3) + 8 * (reg >> 2) + 4 * half;
            gbuf[row * 129 + col] = fmaxf(acc2[reg] + b2, 0.f);
        }
        __syncthreads();
        const int node = t >> 3;
        const int seg  = t & 7;
        const float* gr = gbuf + node * 129 + seg * 16;
        float a = 0.f;
        #pragma unroll
        for (int i = 0; i < 16; ++i) a += gr[i] * f2[seg * 16 + i];
        a += __shfl_down(a, 4, 8);
        a += __shfl_down(a, 2, 8);
        a += __shfl_down(a, 1, 8);
        if (seg == 0) outF[r0 + node] = a + f2b[0];
    }
}

// ---------------- merged prep: wprep + wfoldA + wfoldB + rank-hist ----------
__global__ __launch_bounds__(256) void prep_kernel(
    const float* __restrict__ c0w2, const float* __restrict__ c1w2,
    const float* __restrict__ c1w1, const float* __restrict__ c0w3,
    const float* __restrict__ c0b3, const float* __restrict__ c1b1,
    const float* __restrict__ fw1,  const float* __restrict__ c1w3,
    const float* __restrict__ c1b3, const float* __restrict__ fb1,
    const int* __restrict__ dst, int* __restrict__ cnt, int* __restrict__ rank,
    uint* __restrict__ wp, uint* __restrict__ p_Wa, uint* __restrict__ p_Wb,
    float* __restrict__ f_ba, float* __restrict__ f_bb)
{
    const int b = blockIdx.x;
    const int t = threadIdx.x;
    if (b < 128) {
        int i = b * 256 + t;
        const float* src = (i < 16384) ? c0w2 : c1w2;
        int off = (i < 16384) ? 0 : 16384;
        int L = i - off;
        int o = L >> 7, k = L & 127;
        short hh, ll;
        splits(src[L], &hh, &ll);
        wp[off + wswz(o, k)] = ((uint)(unsigned short)hh << 16) | (uint)(unsigned short)ll;
    } else if (b < 384) {
        const bool isA = (b < 256);
        const int o = b - (isA ? 128 : 256);
        const float* A   = isA ? c1w1 : fw1;
        const float* B   = isA ? c0w3 : c1w3;
        const float* bi  = isA ? c0b3 : c1b3;
        const float* bo  = isA ? c1b1 : fb1;
        uint*  W  = isA ? p_Wa : p_Wb;
        float* bb = isA ? f_ba : f_bb;
        const float* Ar = A + o * 128;
        float s = 0.f;
        for (int j = 0; j < 128; ++j) s += Ar[j] * B[j * 256 + t];
        short hh, ll;
        splits(s, &hh, &ll);
        W[wswz(o, t)] = ((uint)(unsigned short)hh << 16) | (uint)(unsigned short)ll;
        if (t == 0) {
            float sb = 0.f;
            for (int j = 0; j < 128; ++j) sb += Ar[j] * bi[j];
            bb[o] = sb + bo[o];
        }
    } else {
        int e = (b - 384) * 256 + t;
        if (e < NE) rank[e] = atomicAdd(&cnt[dst[e]], 1);
    }
}

// ---------------- single-block full exclusive scan ---------------------------
#define SCHUNK 40   // 1024 threads x 40 >= NN
__global__ __launch_bounds__(1024) void scan_kernel(
    const int* __restrict__ cnt, int* __restrict__ row_ptr)
{
    __shared__ int s[1024];
    const int t = threadIdx.x;
    const int base = t * SCHUNK;
    int sum = 0;
    if (base < NN) {
        int n = min(SCHUNK, NN - base);
        #pragma unroll 8
        for (int j = 0; j < n; ++j) sum += cnt[base + j];
    }
    s[t] = sum;
    __syncthreads();
    #pragma unroll
    for (int off = 1; off < 1024; off <<= 1) {
        int x = (t >= off) ? s[t - off] : 0;
        __syncthreads();
        s[t] += x;
        __syncthreads();
    }
    int run = (t == 0) ? 0 : s[t - 1];
    if (base < NN) {
        int n = min(SCHUNK, NN - base);
        for (int j = 0; j < n; ++j) {
            int v = cnt[base + j];
            row_ptr[base + j] = run;
            run += v;
        }
    }
    if (t == 1023) row_ptr[NN] = s[1023];
}

// ---------------- merged fill (rank-based, no atomics) + embed --------------
__global__ __launch_bounds__(256) void fill_embed_kernel(
    const int* __restrict__ src, const int* __restrict__ dst,
    const int* __restrict__ row_ptr, const int* __restrict__ rank,
    int* __restrict__ esrc,
    const float* __restrict__ x, const float* __restrict__ w1,
    const float* __restrict__ b1, __half* __restrict__ h0)
{
    const int b = blockIdx.x;
    const int t = threadIdx.x;
    if (b < EB) {
        int e = b * 256 + t;
        if (e < NE) {
            int d = dst[e];
            esrc[row_ptr[d] + rank[e]] = src[e];
        }
    } else {
        __shared__ float xs[2][88];
        const int hf = t >> 7;
        const int m  = t & 127;
        const int r0 = (b - EB) * 16 + hf * 8;
        for (int i = m; i < 88; i += 128) {
            int r = i / 11, k = i - r * 11;
            xs[hf][i] = x[(size_t)(r0 + r) * 11 + k];
        }
        __syncthreads();
        float acc[8] = {};
        const float* Wm = w1 + m * 11;
        #pragma unroll
        for (int k = 0; k < 11; ++k) {
            float w = Wm[k];
            #pragma unroll
            for (int r = 0; r < 8; ++r) acc[r] += xs[hf][r * 11 + k] * w;
        }
        const float bias = b1[m];
        #pragma unroll
        for (int r = 0; r < 8; ++r) {
            float v = fmaxf(acc[r] + bias, 0.f);
            h0[(size_t)(r0 + r) * HID + m] = __float2half(v);
        }
    }
}

extern "C" void kernel_launch(void* const* d_in, const int* in_sizes, int n_in,
                              void* d_out, int out_size, void* d_ws, size_t ws_size,
                              hipStream_t stream)
{
    const float* x     = (const float*)d_in[0];
    const int*   eidx  = (const int*)d_in[1];
    const float* c0_w1 = (const float*)d_in[2],  *c0_b1 = (const float*)d_in[3];
    const float* c0_w2 = (const float*)d_in[4],  *c0_b2 = (const float*)d_in[5];
    const float* c0_w3 = (const float*)d_in[6],  *c0_b3 = (const float*)d_in[7];
    const float* c1_w1 = (const float*)d_in[8],  *c1_b1 = (const float*)d_in[9];
    const float* c1_w2 = (const float*)d_in[10], *c1_b2 = (const float*)d_in[11];
    const float* c1_w3 = (const float*)d_in[12], *c1_b3 = (const float*)d_in[13];
    const float* f_w1  = (const float*)d_in[14], *f_b1  = (const float*)d_in[15];
    const float* f_w2  = (const float*)d_in[16], *f_b2  = (const float*)d_in[17];
    const int* src = eidx;
    const int* dst = eidx + NE;
    float* out = (float*)d_out;

    const size_t BUF = (size_t)NN * HID;
    __half* bA = (__half*)d_ws;
    __half* bB = bA + BUF;
    __half* bC = bB + BUF;                   // rank scratch only (fused pipeline)
    int* row_ptr  = (int*)(bC + BUF);        // NN+1
    int* cnt      = row_ptr + (NN + 1);      // NN (hist)
    int* esrc     = cnt + NN;                // NE
    uint* wp      = (uint*)(esrc + NE);

    uint* p_c0w2 = wp + 0;          // 16384
    uint* p_c1w2 = wp + 16384;      // 16384
    uint* p_Wa   = wp + 32768;      // 32768 (c1_w1 · c0_w3)
    uint* p_Wb   = wp + 65536;      // 32768 (f_w1 · c1_w3)
    float* f_ba  = (float*)(wp + 98304);  // 128
    float* f_bb  = f_ba + 128;            // 128

    int* rank = (int*)bC;

    const int nbl = (NN + 31) / 32;   // 1250

    // ---- prep (weights + rank-hist) + scan + fill/embed ----
    (void)hipMemsetAsync(cnt, 0, NN * sizeof(int), stream);
    prep_kernel<<<384 + EB, 256, 0, stream>>>(
        c0_w2, c1_w2, c1_w1, c0_w3, c0_b3, c1_b1,
        f_w1, c1_w3, c1_b3, f_b1, dst, cnt, rank, wp, p_Wa, p_Wb, f_ba, f_bb);
    scan_kernel<<<1, 1024, 0, stream>>>(cnt, row_ptr);
    fill_embed_kernel<<<EB + 2500, 256, 0, stream>>>(
        src, dst, row_ptr, rank, esrc, x, c0_w1, c0_b1, bA);      // h0 = bA

    // ---- conv0: gather l1_0; fused gather l2_0 + folded lin -> h1 (bA) ----
    fused_gather_lin_kernel<<<nbl, 256, 0, stream>>>(bA, row_ptr, esrc, p_c0w2, c0_b2, bB);
    gather2_fused_kernel<false><<<nbl, 256, 0, stream>>>(
        bB, row_ptr, esrc, p_c0w2, c0_b2, p_Wa, f_ba, bA, nullptr, nullptr, nullptr);

    // ---- conv1: gather l1_1; fused gather l2_1 + cat GEMM + head -> out ----
    fused_gather_lin_kernel<<<nbl, 256, 0, stream>>>(bA, row_ptr, esrc, p_c1w2, c1_b2, bB);
    gather2_fused_kernel<true><<<nbl, 256, 0, stream>>>(
        bB, row_ptr, esrc, p_c1w2, c1_b2, p_Wb, f_bb, nullptr, f_w2, f_b2, out);
}

// Round 16
// 297.920 us; speedup vs baseline: 1.0151x; 1.0051x over previous
//
#include <hip/hip_runtime.h>
#include <hip/hip_fp16.h>

#define NN 40000
#define NE 640000
#define HID 128
#define EB ((NE + 255) / 256)         // 2500
#define ECAP 1408                     // staged edge-index capacity per block
#define FS 260                        // fragment group stride (shorts)

typedef __attribute__((ext_vector_type(8)))  short short8;
typedef __attribute__((ext_vector_type(4)))  short short4v;
typedef __attribute__((ext_vector_type(16))) float floatx16;
typedef unsigned int uint;

__device__ __forceinline__ short f2bf(float f) {
    union { float f; unsigned u; } c; c.f = f;
    unsigned u = c.u;
    unsigned r = (u + 0x7FFF + ((u >> 16) & 1)) >> 16;   // RNE
    return (short)r;
}
__device__ __forceinline__ float bf2f(short h) {
    union { unsigned u; float f; } c;
    c.u = ((unsigned)(unsigned short)h) << 16;
    return c.f;
}
__device__ __forceinline__ float2 h2f2(uint u) {
    union { uint u; __half2 h; } c; c.u = u;
    return __half22float2(c.h);
}
// packed fp16 add of two uints holding __half2 (r16: VALU cut in edge loop)
__device__ __forceinline__ uint pk2(uint a, uint b) {
    union { uint u; __half2 h; } x, y, r;
    x.u = a; y.u = b;
    r.h = __hadd2(x.h, y.h);
    return r.u;
}
__device__ __forceinline__ void splits(float f, short* hi, short* lo) {
    short h = f2bf(f);
    *hi = h;
    *lo = f2bf(f - bf2f(h));
}
__device__ __forceinline__ void unpack8(uint4 a, uint4 b, short8* h, short8* l) {
    short8 H, L;
    H[0] = (short)(a.x >> 16); L[0] = (short)a.x;
    H[1] = (short)(a.y >> 16); L[1] = (short)a.y;
    H[2] = (short)(a.z >> 16); L[2] = (short)a.z;
    H[3] = (short)(a.w >> 16); L[3] = (short)a.w;
    H[4] = (short)(b.x >> 16); L[4] = (short)b.x;
    H[5] = (short)(b.y >> 16); L[5] = (short)b.y;
    H[6] = (short)(b.z >> 16); L[6] = (short)b.z;
    H[7] = (short)(b.w >> 16); L[7] = (short)b.w;
    *h = H; *l = L;
}

// W fragment swizzle (HW-verified r9-r15)
__device__ __forceinline__ int wswz(int o, int k) {
    int chunk = k >> 4, half = (k >> 3) & 1, j = k & 7;
    int ct = o >> 5, m31 = o & 31;
    int lane = half * 32 + m31;
    return (((chunk * 4 + ct) * 64 + lane) * 8 + j);
}

// accumulate one uint4 (8 fp16 channels) into two float4 accumulators
#define ACC4(u, A, B)                                                     \
    { float2 f0 = h2f2(u.x), f1 = h2f2(u.y);                              \
      float2 f2 = h2f2(u.z), f3 = h2f2(u.w);                              \
      A.x += f0.x; A.y += f0.y; A.z += f1.x; A.w += f1.y;                 \
      B.x += f2.x; B.y += f2.y; B.z += f3.x; B.w += f3.y; }

// edge loop body. v8: pairwise fp16 pre-sum (u_i + u_{i+4}) via __hadd2 cuts
// VALU 128->80 ops/iter (r15: VALUBusy 31% was the busiest pipe). fp16 add
// of two elements adds <=1e-4 rel error; fp32 accumulation thereafter.
#define GBODY(IDX)                                                        \
        for (; e + 8 <= hi; e += 8) {                                     \
            int s0 = IDX(e + sub);     int s1 = IDX(e + 2 + sub);         \
            int s2 = IDX(e + 4 + sub); int s3 = IDX(e + 6 + sub);         \
            uint4 u0 = hp[(size_t)s0 * 16 + c16];                         \
            uint4 u1 = hp[(size_t)s1 * 16 + c16];                         \
            uint4 u2 = hp[(size_t)s2 * 16 + c16];                         \
            uint4 u3 = hp[(size_t)s3 * 16 + c16];                         \
            uint4 p01, p23;                                               \
            p01.x = pk2(u0.x, u1.x); p01.y = pk2(u0.y, u1.y);             \
            p01.z = pk2(u0.z, u1.z); p01.w = pk2(u0.w, u1.w);             \
            p23.x = pk2(u2.x, u3.x); p23.y = pk2(u2.y, u3.y);             \
            p23.z = pk2(u2.z, u3.z); p23.w = pk2(u2.w, u3.w);             \
            ACC4(p01, a0, a1); ACC4(p23, c0, c1);                         \
        }                                                                 \
        for (; e + 2 <= hi; e += 2) {                                     \
            int s0 = IDX(e + sub);                                        \
            uint4 u0 = hp[(size_t)s0 * 16 + c16];                         \
            ACC4(u0, a0, a1);                                             \
        }                                                                 \
        if (sub == 0 && e < hi) {                                         \
            int s0 = IDX(e);                                              \
            uint4 u0 = hp[(size_t)s0 * 16 + c16];                         \
            ACC4(u0, b0, b1);                                             \
        }

#define IDXS(j) sE[(j)]
#define IDXG(j) esrc[lo0 + (j)]

// edge-gather phase: agg rows -> split-bf16 fragments in groups 0..15
#define GATHER_PHASE                                                          \
    if (t == 0) sCtr = 0;                                                     \
    if (t < 33) sRP[t] = row_ptr[r0 + t];                                     \
    __syncthreads();                                                          \
    const int lo0 = sRP[0];                                                   \
    const int nE  = sRP[32] - lo0;                                            \
    const int nStage = nE < ECAP ? nE : ECAP;                                 \
    for (int i = t; i < nStage; i += 256) sE[i] = esrc[lo0 + i];              \
    __syncthreads();                                                          \
    const bool fast = (nE <= ECAP);                                           \
    for (;;) {                                                                \
        int n = 0;                                                            \
        if ((t & 31) == 0) n = atomicAdd(&sCtr, 1);                           \
        n = __shfl(n, 0, 32);                                                 \
        if (n >= 32) break;                                                   \
        const int lo = sRP[n] - lo0, hi = sRP[n + 1] - lo0;                   \
        float4 a0 = make_float4(0,0,0,0), a1 = make_float4(0,0,0,0);          \
        float4 b0 = make_float4(0,0,0,0), b1 = make_float4(0,0,0,0);          \
        float4 c0 = make_float4(0,0,0,0), c1 = make_float4(0,0,0,0);          \
        int e = lo;                                                           \
        if (fast) { GBODY(IDXS) } else { GBODY(IDXG) }                        \
        float4 v0, v1;                                                        \
        v0.x = (a0.x + b0.x) + c0.x;                                          \
        v0.y = (a0.y + b0.y) + c0.y;                                          \
        v0.z = (a0.z + b0.z) + c0.z;                                          \
        v0.w = (a0.w + b0.w) + c0.w;                                          \
        v1.x = (a1.x + b1.x) + c1.x;                                          \
        v1.y = (a1.y + b1.y) + c1.y;                                          \
        v1.z = (a1.z + b1.z) + c1.z;                                          \
        v1.w = (a1.w + b1.w) + c1.w;                                          \
        v0.x += __shfl_down(v0.x, 16, 32);                                    \
        v0.y += __shfl_down(v0.y, 16, 32);                                    \
        v0.z += __shfl_down(v0.z, 16, 32);                                    \
        v0.w += __shfl_down(v0.w, 16, 32);                                    \
        v1.x += __shfl_down(v1.x, 16, 32);                                    \
        v1.y += __shfl_down(v1.y, 16, 32);                                    \
        v1.z += __shfl_down(v1.z, 16, 32);                                    \
        v1.w += __shfl_down(v1.w, 16, 32);                                    \
        if (sub == 0) {                                                       \
            short8 H, L;                                                      \
            short hh, ll;                                                     \
            splits(v0.x, &hh, &ll); H[0] = hh; L[0] = ll;                     \
            splits(v0.y, &hh, &ll); H[1] = hh; L[1] = ll;                     \
            splits(v0.z, &hh, &ll); H[2] = hh; L[2] = ll;                     \
            splits(v0.w, &hh, &ll); H[3] = hh; L[3] = ll;                     \
            splits(v1.x, &hh, &ll); H[4] = hh; L[4] = ll;                     \
            splits(v1.y, &hh, &ll); H[5] = hh; L[5] = ll;                     \
            splits(v1.z, &hh, &ll); H[6] = hh; L[6] = ll;                     \
            splits(v1.w, &hh, &ll); H[7] = hh; L[7] = ll;                     \
            const int off = c16 * FS + n * 8;                                 \
            *(short8*)(sAh + off) = H;                                        \
            *(short8*)(sAl + off) = L;                                        \
        }                                                                     \
    }                                                                         \
    __syncthreads();

#define MFMA_LOOP(NC, WQ, ACC)                                                \
    _Pragma("unroll")                                                         \
    for (int c = 0; c < NC; ++c) {                                            \
        short8 ah = *(const short8*)(sAh + (c * 2 + half) * FS + m31 * 8);    \
        short8 al = *(const short8*)(sAl + (c * 2 + half) * FS + m31 * 8);    \
        const uint* wr = WQ + ((size_t)(c * 4 + wv) * 64 + lane) * 8;         \
        uint4 w0 = *(const uint4*)(wr);                                       \
        uint4 w1 = *(const uint4*)(wr + 4);                                   \
        short8 bh, bl;                                                        \
        unpack8(w0, w1, &bh, &bl);                                            \
        ACC = __builtin_amdgcn_mfma_f32_32x32x16_bf16(ah, bh, ACC, 0, 0, 0);  \
        ACC = __builtin_amdgcn_mfma_f32_32x32x16_bf16(al, bh, ACC, 0, 0, 0);  \
        ACC = __builtin_amdgcn_mfma_f32_32x32x16_bf16(ah, bl, ACC, 0, 0, 0);  \
    }

// ---------------- gather #1: fused gather + W2 linear -> fp16 global --------
__global__ __launch_bounds__(256, 4) void fused_gather_lin_kernel(
    const __half* __restrict__ h, const int* __restrict__ row_ptr,
    const int* __restrict__ esrc, const uint* __restrict__ Wq,
    const float* __restrict__ bias, __half* __restrict__ out)
{
    __shared__ short sAh[16 * FS];
    __shared__ short sAl[16 * FS];
    __shared__ int   sE[ECAP];
    __shared__ int   sRP[33];
    __shared__ int   sCtr;
    const int t   = threadIdx.x;
    const int r0  = blockIdx.x * 32;
    const int c16 = t & 15;
    const int sub = (t >> 4) & 1;
    const uint4* hp = (const uint4*)h;   // row = 16 uint4

    GATHER_PHASE

    const int wv   = t >> 6;
    const int lane = t & 63;
    const int m31  = lane & 31;
    const int half = lane >> 5;
    floatx16 acc;
    #pragma unroll
    for (int i = 0; i < 16; ++i) acc[i] = 0.f;
    MFMA_LOOP(8, Wq, acc)
    const int col = wv * 32 + m31;
    const float bb = bias[col];
    #pragma unroll
    for (int reg = 0; reg < 16; ++reg) {
        int row = (reg & 3) + 8 * (reg >> 2) + 4 * half;
        float v = fmaxf(acc[reg] + bb, 0.f);
        out[(size_t)(r0 + row) * HID + col] = __float2half(v);
    }
}

// ---------------- gather #2 fused with folded linear / cat+head -------------
template<bool HEAD>
__global__ __launch_bounds__(256, HEAD ? 3 : 4) void gather2_fused_kernel(
    const __half* __restrict__ h, const int* __restrict__ row_ptr,
    const int* __restrict__ esrc, const uint* __restrict__ Wq,
    const float* __restrict__ bias, const uint* __restrict__ Wq2,
    const float* __restrict__ bias2, __half* __restrict__ outA,
    const float* __restrict__ f2, const float* __restrict__ f2b,
    float* __restrict__ outF)
{
    __shared__ short sAh[32 * FS];
    __shared__ short sAl[32 * FS];
    __shared__ __align__(16) char upool[HEAD ? (32 * 129 * 4) : (ECAP * 4)];
    __shared__ int   sRP[33];
    __shared__ int   sCtr;
    int*   sE   = (int*)upool;            // edge loop only
    float* gbuf = (float*)upool;          // HEAD tail only (sE dead by then)
    const int t   = threadIdx.x;
    const int r0  = blockIdx.x * 32;
    const int c16 = t & 15;
    const int sub = (t >> 4) & 1;
    const uint4* hp = (const uint4*)h;    // row = 16 uint4

    GATHER_PHASE                          // ends with S1

    const int wv   = t >> 6;
    const int lane = t & 63;
    const int m31  = lane & 31;
    const int half = lane >> 5;
    const int col  = wv * 32 + m31;

    // MFMA#1: l2 = relu(W2 . agg + b2); write fragments to groups 16..31.
    {
        floatx16 acc1;
        #pragma unroll
        for (int i = 0; i < 16; ++i) acc1[i] = 0.f;
        MFMA_LOOP(8, Wq, acc1)
        const float bb = bias[col];
        #pragma unroll
        for (int reg = 0; reg < 16; ++reg) {
            int row = (reg & 3) + 8 * (reg >> 2) + 4 * half;
            float v = fmaxf(acc1[reg] + bb, 0.f);
            short hh, ll;
            splits(v, &hh, &ll);
            int off2 = (16 + (col >> 3)) * FS + row * 8 + (col & 7);
            sAh[off2] = hh;
            sAl[off2] = ll;
        }
    }
    __syncthreads();   // S2: MFMA#1 reads + l2 writes complete

    // stage l1 (= h rows r0..r0+31) into groups 0..15
    #pragma unroll
    for (int i = 0; i < 4; ++i) {
        int v = t + 256 * i;              // 0..1023
        int row = v >> 5, q = v & 31;     // kk = q*4
        uint2 u = *(const uint2*)((const __half*)h + (size_t)(r0 + row) * 128 + q * 4);
        float2 f0 = h2f2(u.x), f1 = h2f2(u.y);
        int off = (q >> 1) * FS + row * 8 + (q & 1) * 4;
        short4v hi, lo;
        short hh, ll;
        splits(f0.x, &hh, &ll); hi.x = hh; lo.x = ll;
        splits(f0.y, &hh, &ll); hi.y = hh; lo.y = ll;
        splits(f1.x, &hh, &ll); hi.z = hh; lo.z = ll;
        splits(f1.y, &hh, &ll); hi.w = hh; lo.w = ll;
        *(short4v*)(sAh + off) = hi;
        *(short4v*)(sAl + off) = lo;
    }
    __syncthreads();   // S3: cat(l1,l2) fragments ready

    floatx16 acc2;
    #pragma unroll
    for (int i = 0; i < 16; ++i) acc2[i] = 0.f;
    MFMA_LOOP(16, Wq2, acc2)

    const float b2 = bias2[col];
    if (!HEAD) {
        #pragma unroll
        for (int reg = 0; reg < 16; ++reg) {
            int row = (reg & 3) + 8 * (reg >> 2) + 4 * half;
            float v = fmaxf(acc2[reg] + b2, 0.f);
            outA[(size_t)(r0 + row) * HID + col] = __float2half(v);
        }
    } else {
        #pragma unroll
        for (int reg = 0; reg < 16; ++reg) {
            int row = (reg & 3) + 8 * (reg >> 2) + 4 * half;
            gbuf[row * 129 + col] = fmaxf(acc2[reg] + b2, 0.f);
        }
        __syncthreads();
        const int node = t >> 3;
        const int seg  = t & 7;
        const float* gr = gbuf + node * 129 + seg * 16;
        float a = 0.f;
        #pragma unroll
        for (int i = 0; i < 16; ++i) a += gr[i] * f2[seg * 16 + i];
        a += __shfl_down(a, 4, 8);
        a += __shfl_down(a, 2, 8);
        a += __shfl_down(a, 1, 8);
        if (seg == 0) outF[r0 + node] = a + f2b[0];
    }
}

// ---------------- merged prep: wprep + wfoldA + wfoldB + rank-hist ----------
__global__ __launch_bounds__(256) void prep_kernel(
    const float* __restrict__ c0w2, const float* __restrict__ c1w2,
    const float* __restrict__ c1w1, const float* __restrict__ c0w3,
    const float* __restrict__ c0b3, const float* __restrict__ c1b1,
    const float* __restrict__ fw1,  const float* __restrict__ c1w3,
    const float* __restrict__ c1b3, const float* __restrict__ fb1,
    const int* __restrict__ dst, int* __restrict__ cnt, int* __restrict__ rank,
    uint* __restrict__ wp, uint* __restrict__ p_Wa, uint* __restrict__ p_Wb,
    float* __restrict__ f_ba, float* __restrict__ f_bb)
{
    const int b = blockIdx.x;
    const int t = threadIdx.x;
    if (b < 128) {
        int i = b * 256 + t;
        const float* src = (i < 16384) ? c0w2 : c1w2;
        int off = (i < 16384) ? 0 : 16384;
        int L = i - off;
        int o = L >> 7, k = L & 127;
        short hh, ll;
        splits(src[L], &hh, &ll);
        wp[off + wswz(o, k)] = ((uint)(unsigned short)hh << 16) | (uint)(unsigned short)ll;
    } else if (b < 384) {
        const bool isA = (b < 256);
        const int o = b - (isA ? 128 : 256);
        const float* A   = isA ? c1w1 : fw1;
        const float* B   = isA ? c0w3 : c1w3;
        const float* bi  = isA ? c0b3 : c1b3;
        const float* bo  = isA ? c1b1 : fb1;
        uint*  W  = isA ? p_Wa : p_Wb;
        float* bb = isA ? f_ba : f_bb;
        const float* Ar = A + o * 128;
        float s = 0.f;
        for (int j = 0; j < 128; ++j) s += Ar[j] * B[j * 256 + t];
        short hh, ll;
        splits(s, &hh, &ll);
        W[wswz(o, t)] = ((uint)(unsigned short)hh << 16) | (uint)(unsigned short)ll;
        if (t == 0) {
            float sb = 0.f;
            for (int j = 0; j < 128; ++j) sb += Ar[j] * bi[j];
            bb[o] = sb + bo[o];
        }
    } else {
        int e = (b - 384) * 256 + t;
        if (e < NE) rank[e] = atomicAdd(&cnt[dst[e]], 1);
    }
}

// ---------------- single-block full exclusive scan ---------------------------
#define SCHUNK 40   // 1024 threads x 40 >= NN
__global__ __launch_bounds__(1024) void scan_kernel(
    const int* __restrict__ cnt, int* __restrict__ row_ptr)
{
    __shared__ int s[1024];
    const int t = threadIdx.x;
    const int base = t * SCHUNK;
    int sum = 0;
    if (base < NN) {
        int n = min(SCHUNK, NN - base);
        #pragma unroll 8
        for (int j = 0; j < n; ++j) sum += cnt[base + j];
    }
    s[t] = sum;
    __syncthreads();
    #pragma unroll
    for (int off = 1; off < 1024; off <<= 1) {
        int x = (t >= off) ? s[t - off] : 0;
        __syncthreads();
        s[t] += x;
        __syncthreads();
    }
    int run = (t == 0) ? 0 : s[t - 1];
    if (base < NN) {
        int n = min(SCHUNK, NN - base);
        for (int j = 0; j < n; ++j) {
            int v = cnt[base + j];
            row_ptr[base + j] = run;
            run += v;
        }
    }
    if (t == 1023) row_ptr[NN] = s[1023];
}

// ---------------- merged fill (rank-based, no atomics) + embed --------------
__global__ __launch_bounds__(256) void fill_embed_kernel(
    const int* __restrict__ src, const int* __restrict__ dst,
    const int* __restrict__ row_ptr, const int* __restrict__ rank,
    int* __restrict__ esrc,
    const float* __restrict__ x, const float* __restrict__ w1,
    const float* __restrict__ b1, __half* __restrict__ h0)
{
    const int b = blockIdx.x;
    const int t = threadIdx.x;
    if (b < EB) {
        int e = b * 256 + t;
        if (e < NE) {
            int d = dst[e];
            esrc[row_ptr[d] + rank[e]] = src[e];
        }
    } else {
        __shared__ float xs[2][88];
        const int hf = t >> 7;
        const int m  = t & 127;
        const int r0 = (b - EB) * 16 + hf * 8;
        for (int i = m; i < 88; i += 128) {
            int r = i / 11, k = i - r * 11;
            xs[hf][i] = x[(size_t)(r0 + r) * 11 + k];
        }
        __syncthreads();
        float acc[8] = {};
        const float* Wm = w1 + m * 11;
        #pragma unroll
        for (int k = 0; k < 11; ++k) {
            float w = Wm[k];
            #pragma unroll
            for (int r = 0; r < 8; ++r) acc[r] += xs[hf][r * 11 + k] * w;
        }
        const float bias = b1[m];
        #pragma unroll
        for (int r = 0; r < 8; ++r) {
            float v = fmaxf(acc[r] + bias, 0.f);
            h0[(size_t)(r0 + r) * HID + m] = __float2half(v);
        }
    }
}

extern "C" void kernel_launch(void* const* d_in, const int* in_sizes, int n_in,
                              void* d_out, int out_size, void* d_ws, size_t ws_size,
                              hipStream_t stream)
{
    const float* x     = (const float*)d_in[0];
    const int*   eidx  = (const int*)d_in[1];
    const float* c0_w1 = (const float*)d_in[2],  *c0_b1 = (const float*)d_in[3];
    const float* c0_w2 = (const float*)d_in[4],  *c0_b2 = (const float*)d_in[5];
    const float* c0_w3 = (const float*)d_in[6],  *c0_b3 = (const float*)d_in[7];
    const float* c1_w1 = (const float*)d_in[8],  *c1_b1 = (const float*)d_in[9];
    const float* c1_w2 = (const float*)d_in[10], *c1_b2 = (const float*)d_in[11];
    const float* c1_w3 = (const float*)d_in[12], *c1_b3 = (const float*)d_in[13];
    const float* f_w1  = (const float*)d_in[14], *f_b1  = (const float*)d_in[15];
    const float* f_w2  = (const float*)d_in[16], *f_b2  = (const float*)d_in[17];
    const int* src = eidx;
    const int* dst = eidx + NE;
    float* out = (float*)d_out;

    const size_t BUF = (size_t)NN * HID;
    __half* bA = (__half*)d_ws;
    __half* bB = bA + BUF;
    __half* bC = bB + BUF;                   // rank scratch only (fused pipeline)
    int* row_ptr  = (int*)(bC + BUF);        // NN+1
    int* cnt      = row_ptr + (NN + 1);      // NN (hist)
    int* esrc     = cnt + NN;                // NE
    uint* wp      = (uint*)(esrc + NE);

    uint* p_c0w2 = wp + 0;          // 16384
    uint* p_c1w2 = wp + 16384;      // 16384
    uint* p_Wa   = wp + 32768;      // 32768 (c1_w1 · c0_w3)
    uint* p_Wb   = wp + 65536;      // 32768 (f_w1 · c1_w3)
    float* f_ba  = (float*)(wp + 98304);  // 128
    float* f_bb  = f_ba + 128;            // 128

    int* rank = (int*)bC;

    const int nbl = (NN + 31) / 32;   // 1250

    // ---- prep (weights + rank-hist) + scan + fill/embed ----
    (void)hipMemsetAsync(cnt, 0, NN * sizeof(int), stream);
    prep_kernel<<<384 + EB, 256, 0, stream>>>(
        c0_w2, c1_w2, c1_w1, c0_w3, c0_b3, c1_b1,
        f_w1, c1_w3, c1_b3, f_b1, dst, cnt, rank, wp, p_Wa, p_Wb, f_ba, f_bb);
    scan_kernel<<<1, 1024, 0, stream>>>(cnt, row_ptr);
    fill_embed_kernel<<<EB + 2500, 256, 0, stream>>>(
        src, dst, row_ptr, rank, esrc, x, c0_w1, c0_b1, bA);      // h0 = bA

    // ---- conv0: gather l1_0; fused gather l2_0 + folded lin -> h1 (bA) ----
    fused_gather_lin_kernel<<<nbl, 256, 0, stream>>>(bA, row_ptr, esrc, p_c0w2, c0_b2, bB);
    gather2_fused_kernel<false><<<nbl, 256, 0, stream>>>(
        bB, row_ptr, esrc, p_c0w2, c0_b2, p_Wa, f_ba, bA, nullptr, nullptr, nullptr);

    // ---- conv1: gather l1_1; fused gather l2_1 + cat GEMM + head -> out ----
    fused_gather_lin_kernel<<<nbl, 256, 0, stream>>>(bA, row_ptr, esrc, p_c1w2, c1_b2, bB);
    gather2_fused_kernel<true><<<nbl, 256, 0, stream>>>(
        bB, row_ptr, esrc, p_c1w2, c1_b2, p_Wb, f_bb, nullptr, f_w2, f_b2, out);
}